// Round 1
// baseline (943.822 us; speedup 1.0000x reference)
//
#include <hip/hip_runtime.h>
#include <hip/hip_bf16.h>
#include <math.h>

#define NF 128   // IN_F == HID == 128

static inline int ceil_div(int a, int b) { return (a + b - 1) / b; }

// ---------------- degree / CSR build ----------------
__global__ void hist_deg_kernel(const int* __restrict__ dst, int* __restrict__ degi, int e) {
  int i = blockIdx.x * 256 + threadIdx.x;
  if (i < e) atomicAdd(&degi[dst[i]], 1);
}

__global__ void dinv_kernel(const int* __restrict__ degi, float* __restrict__ dinv, int n) {
  int i = blockIdx.x * 256 + threadIdx.x;
  if (i < n) {
    float d = (float)(degi[i] > 1 ? degi[i] : 1);
    dinv[i] = rsqrtf(d);
  }
}

__global__ void scan_partials_kernel(const int* __restrict__ degi, int* __restrict__ partials, int n) {
  __shared__ int sh[256];
  int i = blockIdx.x * 256 + threadIdx.x;
  sh[threadIdx.x] = (i < n) ? degi[i] : 0;
  __syncthreads();
  for (int s = 128; s > 0; s >>= 1) {
    if (threadIdx.x < s) sh[threadIdx.x] += sh[threadIdx.x + s];
    __syncthreads();
  }
  if (threadIdx.x == 0) partials[blockIdx.x] = sh[0];
}

// exclusive scan of up to 256 block partials (N <= 65536 ok; here N=50000 -> 196 blocks)
__global__ void scan_block_kernel(int* __restrict__ partials, int nb) {
  __shared__ int sh[256];
  int t = threadIdx.x;
  int v = (t < nb) ? partials[t] : 0;
  sh[t] = v;
  __syncthreads();
  for (int off = 1; off < 256; off <<= 1) {
    int add = (t >= off) ? sh[t - off] : 0;
    __syncthreads();
    sh[t] += add;
    __syncthreads();
  }
  if (t < nb) partials[t] = sh[t] - v;   // exclusive
}

__global__ void scan_final_kernel(const int* __restrict__ degi, const int* __restrict__ partials,
                                  int* __restrict__ offsets, int n) {
  __shared__ int sh[256];
  int i = blockIdx.x * 256 + threadIdx.x;
  int v = (i < n) ? degi[i] : 0;
  sh[threadIdx.x] = v;
  __syncthreads();
  for (int off = 1; off < 256; off <<= 1) {
    int add = (threadIdx.x >= off) ? sh[threadIdx.x - off] : 0;
    __syncthreads();
    sh[threadIdx.x] += add;
    __syncthreads();
  }
  if (i < n) offsets[i] = partials[blockIdx.x] + sh[threadIdx.x] - v;
}

__global__ void cursor_init_kernel(const int* __restrict__ offsets, int* __restrict__ cursor,
                                   int* __restrict__ offsets_n, int n, int e) {
  int i = blockIdx.x * 256 + threadIdx.x;
  if (i < n) cursor[i] = offsets[i];
  if (i == 0) *offsets_n = e;   // offsets[n] = E
}

__global__ void scatter_kernel(const int* __restrict__ src, const int* __restrict__ dst,
                               int* __restrict__ cursor, int* __restrict__ csr_src, int e) {
  int i = blockIdx.x * 256 + threadIdx.x;
  if (i < e) {
    int pos = atomicAdd(&cursor[dst[i]], 1);
    csr_src[pos] = src[i];
  }
}

// ---------------- SpMV: out[v][f] = a * dinv[v] * sum_{e: dst=v} x[src_e][f]*dinv[src_e] + bz*z[v][f]
__global__ void spmv_kernel(const float* __restrict__ x, const float* __restrict__ dinv,
                            const int* __restrict__ offsets, const int* __restrict__ csr,
                            const float* __restrict__ z, float a, float bz,
                            float* __restrict__ out, int n) {
  int node = blockIdx.x;
  if (node >= n) return;
  int f = threadIdx.x;   // 128
  int beg = offsets[node], end = offsets[node + 1];
  float acc = 0.f;
  for (int e2 = beg; e2 < end; ++e2) {
    int s = csr[e2];
    float w = dinv[s];
    acc += x[s * NF + f] * w;
  }
  float v = a * dinv[node] * acc;
  if (z) v += bz * z[node * NF + f];
  out[node * NF + f] = v;
}

// ---------------- weight transpose: W[rows][cols] -> Wt[cols][rows]
__global__ void transpose_w_kernel(const float* __restrict__ W, float* __restrict__ Wt,
                                   int rows, int cols) {
  int i = blockIdx.x * 256 + threadIdx.x;
  if (i < rows * cols) {
    int r = i / cols, c = i % cols;
    Wt[c * rows + r] = W[i];
  }
}

// ---------------- GEMM: out[N][NC] = epi( sum_p Xp[N][128] @ Wt[p*128..][NC] + bias )
// Wt layout: [K][NC] (i.e. original W[c][k] transposed). epilogue: relu then +res.
template<int NC, int NPART>
__global__ __launch_bounds__(256) void gemm_kernel(
    const float* __restrict__ X0, const float* __restrict__ X1, const float* __restrict__ X2,
    const float* __restrict__ Wt, const float* __restrict__ bias,
    const float* __restrict__ res, float* __restrict__ out, int n, int relu) {
  constexpr int CT  = NC / 8;        // threads along cols (8 cols each)
  constexpr int RTH = 256 / CT;      // threads along rows
  constexpr int RT  = RTH * 4;       // rows per block (4 rows each)
  __shared__ float Xs[RT][33];
  __shared__ __align__(16) float Ws[32][NC + 4];

  int tid = threadIdx.x;
  int tc = tid % CT, tr = tid / CT;
  int r0 = blockIdx.x * RT;

  float acc[4][8];
#pragma unroll
  for (int i = 0; i < 4; ++i)
#pragma unroll
    for (int j = 0; j < 8; ++j) acc[i][j] = 0.f;

  const float* Xp[3] = {X0, X1, X2};
#pragma unroll 1
  for (int p = 0; p < NPART; ++p) {
    const float* __restrict__ X = Xp[p];
#pragma unroll 1
    for (int kc = 0; kc < 128; kc += 32) {
      // stage X tile: RT x 32
#pragma unroll
      for (int it = 0; it < (RT * 32) / 256; ++it) {
        int l = tid + it * 256;
        int rr = l >> 5, cc = l & 31;
        int gr = r0 + rr;
        Xs[rr][cc] = (gr < n) ? X[gr * NF + kc + cc] : 0.f;
      }
      // stage W tile: 32 x NC
#pragma unroll
      for (int it = 0; it < (32 * NC) / 256; ++it) {
        int l = tid + it * 256;
        int kk = l / NC, cc = l % NC;
        Ws[kk][cc] = Wt[(p * 128 + kc + kk) * NC + cc];
      }
      __syncthreads();
#pragma unroll
      for (int k = 0; k < 32; ++k) {
        float a[4];
#pragma unroll
        for (int i = 0; i < 4; ++i) a[i] = Xs[tr * 4 + i][k];
        float4 b0 = *(const float4*)&Ws[k][tc * 8];
        float4 b1 = *(const float4*)&Ws[k][tc * 8 + 4];
#pragma unroll
        for (int i = 0; i < 4; ++i) {
          acc[i][0] += a[i] * b0.x;
          acc[i][1] += a[i] * b0.y;
          acc[i][2] += a[i] * b0.z;
          acc[i][3] += a[i] * b0.w;
          acc[i][4] += a[i] * b1.x;
          acc[i][5] += a[i] * b1.y;
          acc[i][6] += a[i] * b1.z;
          acc[i][7] += a[i] * b1.w;
        }
      }
      __syncthreads();
    }
  }
#pragma unroll
  for (int i = 0; i < 4; ++i) {
    int r = r0 + tr * 4 + i;
    if (r < n) {
#pragma unroll
      for (int j = 0; j < 8; ++j) {
        int c = tc * 8 + j;
        float v = acc[i][j] + bias[c];
        if (relu) v = fmaxf(v, 0.f);
        if (res) v += res[r * NC + c];
        out[r * NC + c] = v;
      }
    }
  }
}

// ---------------- BatchNorm ----------------
__global__ void bn_stats_kernel(const float* __restrict__ x, float* __restrict__ stats, int n) {
  int c = threadIdx.x;   // 128
  float s = 0.f, s2 = 0.f;
  for (int r = blockIdx.x; r < n; r += gridDim.x) {
    float v = x[r * NF + c];
    s += v;
    s2 += v * v;
  }
  atomicAdd(&stats[c], s);
  atomicAdd(&stats[NF + c], s2);
}

__global__ void bn_scale_kernel(const float* __restrict__ stats, const float* __restrict__ gamma,
                                const float* __restrict__ beta, float* __restrict__ sc,
                                float* __restrict__ sh, float n) {
  int c = threadIdx.x;   // 128
  float mu = stats[c] / n;
  float var = stats[NF + c] / n - mu * mu;
  float s = gamma[c] * rsqrtf(var + 1e-5f);
  sc[c] = s;
  sh[c] = beta[c] - mu * s;
}

__global__ void bn_apply_kernel(float* __restrict__ x, const float* __restrict__ sc,
                                const float* __restrict__ sh, int total) {
  int i = blockIdx.x * 256 + threadIdx.x;
  if (i < total) {
    int c = i & (NF - 1);
    x[i] = x[i] * sc[c] + sh[c];
  }
}

// ---------------- launcher ----------------
extern "C" void kernel_launch(void* const* d_in, const int* in_sizes, int n_in,
                              void* d_out, int out_size, void* d_ws, size_t ws_size,
                              hipStream_t stream) {
  const float* feat  = (const float*)d_in[0];
  const int*   src   = (const int*)d_in[1];
  const int*   dst   = (const int*)d_in[2];
  const float* W1    = (const float*)d_in[3];
  const float* b1    = (const float*)d_in[4];
  const float* W3    = (const float*)d_in[5];
  const float* b3    = (const float*)d_in[6];
  const float* gamma = (const float*)d_in[7];
  const float* beta  = (const float*)d_in[8];
  const float* Wm1   = (const float*)d_in[9];
  const float* bm1   = (const float*)d_in[10];
  const float* Wm2   = (const float*)d_in[11];
  const float* bm2   = (const float*)d_in[12];
  int n = in_sizes[0] / NF;
  int e = in_sizes[1];

  char* p = (char*)d_ws;
  auto alloc = [&](size_t bytes) {
    char* r = p;
    p += (bytes + 255) & ~size_t(255);
    return r;
  };
  int*   degi     = (int*)alloc((size_t)n * 4);
  float* dinv     = (float*)alloc((size_t)n * 4);
  int*   offsets  = (int*)alloc((size_t)(n + 1) * 4);
  int*   cursor   = (int*)alloc((size_t)n * 4);
  int*   partials = (int*)alloc(256 * 4);
  int*   csr      = (int*)alloc((size_t)e * 4);
  float* stats    = (float*)alloc(256 * 4);
  float* bnsc     = (float*)alloc(128 * 4);
  float* bnsh     = (float*)alloc(128 * 4);
  float* Wt1      = (float*)alloc(384 * 128 * 4);
  float* Wt3      = (float*)alloc(384 * 128 * 4);
  float* Wm1t     = (float*)alloc(128 * 128 * 4);
  float* Wm2t     = (float*)alloc(128 * 64 * 4);
  size_t matb = (size_t)n * NF * 4;
  float* T1 = (float*)alloc(matb);
  float* T2 = (float*)alloc(matb);
  float* X  = (float*)alloc(matb);   // conv1 out -> BN in-place -> x_res
  float* Y  = (float*)alloc(matb);   // conv2 out + residual

  hipMemsetAsync(degi, 0, (size_t)n * 4, stream);
  hipMemsetAsync(stats, 0, 256 * 4, stream);

  int eb = ceil_div(e, 256), nb = ceil_div(n, 256);

  // degree + dinv + CSR (sorted by dst)
  hist_deg_kernel<<<eb, 256, 0, stream>>>(dst, degi, e);
  dinv_kernel<<<nb, 256, 0, stream>>>(degi, dinv, n);
  scan_partials_kernel<<<nb, 256, 0, stream>>>(degi, partials, n);
  scan_block_kernel<<<1, 256, 0, stream>>>(partials, nb);
  scan_final_kernel<<<nb, 256, 0, stream>>>(degi, partials, offsets, n);
  cursor_init_kernel<<<nb, 256, 0, stream>>>(offsets, cursor, offsets + n, n, e);
  scatter_kernel<<<eb, 256, 0, stream>>>(src, dst, cursor, csr, e);

  // weight transposes (tiny)
  transpose_w_kernel<<<ceil_div(128 * 384, 256), 256, 0, stream>>>(W1, Wt1, 128, 384);
  transpose_w_kernel<<<ceil_div(128 * 384, 256), 256, 0, stream>>>(W3, Wt3, 128, 384);
  transpose_w_kernel<<<ceil_div(128 * 128, 256), 256, 0, stream>>>(Wm1, Wm1t, 128, 128);
  transpose_w_kernel<<<ceil_div(64 * 128, 256), 256, 0, stream>>>(Wm2, Wm2t, 64, 128);

  // conv1: T1 = -A^ F ; T2 = -2 A^ T1 - F ; X = relu([F,T1,T2] @ W1^T + b1)
  spmv_kernel<<<n, 128, 0, stream>>>(feat, dinv, offsets, csr, nullptr, -1.f, 0.f, T1, n);
  spmv_kernel<<<n, 128, 0, stream>>>(T1, dinv, offsets, csr, feat, -2.f, -1.f, T2, n);
  gemm_kernel<128, 3><<<ceil_div(n, 64), 256, 0, stream>>>(feat, T1, T2, Wt1, b1, nullptr, X, n, 1);

  // BatchNorm (training stats, biased var), in-place; X becomes x_res
  bn_stats_kernel<<<512, 128, 0, stream>>>(X, stats, n);
  bn_scale_kernel<<<1, 128, 0, stream>>>(stats, gamma, beta, bnsc, bnsh, (float)n);
  bn_apply_kernel<<<ceil_div(n * NF, 256), 256, 0, stream>>>(X, bnsc, bnsh, n * NF);

  // conv2 + residual: Y = relu([X,T1,T2] @ W3^T + b3) + X
  spmv_kernel<<<n, 128, 0, stream>>>(X, dinv, offsets, csr, nullptr, -1.f, 0.f, T1, n);
  spmv_kernel<<<n, 128, 0, stream>>>(T1, dinv, offsets, csr, X, -2.f, -1.f, T2, n);
  gemm_kernel<128, 3><<<ceil_div(n, 64), 256, 0, stream>>>(X, T1, T2, Wt3, b3, X, Y, n, 1);

  // MLP: h = relu(Y @ Wm1^T + bm1) ; out = h @ Wm2^T + bm2
  gemm_kernel<128, 1><<<ceil_div(n, 64), 256, 0, stream>>>(Y, nullptr, nullptr, Wm1t, bm1, nullptr, T1, n, 1);
  gemm_kernel<64, 1><<<ceil_div(n, 128), 256, 0, stream>>>(T1, nullptr, nullptr, Wm2t, bm2, nullptr, (float*)d_out, n, 0);
}

// Round 2
// 507.628 us; speedup vs baseline: 1.8593x; 1.8593x over previous
//
#include <hip/hip_runtime.h>
#include <hip/hip_bf16.h>
#include <math.h>

#define NF 128   // IN_F == HID == 128

typedef __bf16 bf16x8 __attribute__((ext_vector_type(8)));
typedef unsigned short ushort8 __attribute__((ext_vector_type(8)));
typedef float f32x4 __attribute__((ext_vector_type(4)));

static inline int ceil_div(int a, int b) { return (a + b - 1) / b; }

// ---------------- degree / CSR build ----------------
__global__ void hist_deg_kernel(const int* __restrict__ dst, int* __restrict__ degi, int e) {
  int i = blockIdx.x * 256 + threadIdx.x;
  if (i < e) atomicAdd(&degi[dst[i]], 1);
}

__global__ void dinv_kernel(const int* __restrict__ degi, float* __restrict__ dinv, int n) {
  int i = blockIdx.x * 256 + threadIdx.x;
  if (i < n) {
    float d = (float)(degi[i] > 1 ? degi[i] : 1);
    dinv[i] = rsqrtf(d);
  }
}

__global__ void scan_partials_kernel(const int* __restrict__ degi, int* __restrict__ partials, int n) {
  __shared__ int sh[256];
  int i = blockIdx.x * 256 + threadIdx.x;
  sh[threadIdx.x] = (i < n) ? degi[i] : 0;
  __syncthreads();
  for (int s = 128; s > 0; s >>= 1) {
    if (threadIdx.x < s) sh[threadIdx.x] += sh[threadIdx.x + s];
    __syncthreads();
  }
  if (threadIdx.x == 0) partials[blockIdx.x] = sh[0];
}

__global__ void scan_block_kernel(int* __restrict__ partials, int nb) {
  __shared__ int sh[256];
  int t = threadIdx.x;
  int v = (t < nb) ? partials[t] : 0;
  sh[t] = v;
  __syncthreads();
  for (int off = 1; off < 256; off <<= 1) {
    int add = (t >= off) ? sh[t - off] : 0;
    __syncthreads();
    sh[t] += add;
    __syncthreads();
  }
  if (t < nb) partials[t] = sh[t] - v;   // exclusive
}

__global__ void scan_final_kernel(const int* __restrict__ degi, const int* __restrict__ partials,
                                  int* __restrict__ offsets, int n) {
  __shared__ int sh[256];
  int i = blockIdx.x * 256 + threadIdx.x;
  int v = (i < n) ? degi[i] : 0;
  sh[threadIdx.x] = v;
  __syncthreads();
  for (int off = 1; off < 256; off <<= 1) {
    int add = (threadIdx.x >= off) ? sh[threadIdx.x - off] : 0;
    __syncthreads();
    sh[threadIdx.x] += add;
    __syncthreads();
  }
  if (i < n) offsets[i] = partials[blockIdx.x] + sh[threadIdx.x] - v;
}

__global__ void cursor_init_kernel(const int* __restrict__ offsets, int* __restrict__ cursor,
                                   int* __restrict__ offsets_n, int n, int e) {
  int i = blockIdx.x * 256 + threadIdx.x;
  if (i < n) cursor[i] = offsets[i];
  if (i == 0) *offsets_n = e;
}

__global__ void scatter_kernel(const int* __restrict__ src, const int* __restrict__ dst,
                               int* __restrict__ cursor, int* __restrict__ csr_src, int e) {
  int i = blockIdx.x * 256 + threadIdx.x;
  if (i < e) {
    int pos = atomicAdd(&cursor[dst[i]], 1);
    csr_src[pos] = src[i];
  }
}

// ---------------- row scale: out = x * dinv[row] (float4 vectorized) ----------------
__global__ void scale_rows_kernel(const float* __restrict__ x, const float* __restrict__ dinv,
                                  float* __restrict__ out, int n) {
  int i = blockIdx.x * 256 + threadIdx.x;   // float4 index, 32 per row
  if (i < n * (NF / 4)) {
    int row = i >> 5;
    float4 v = ((const float4*)x)[i];
    float d = dinv[row];
    v.x *= d; v.y *= d; v.z *= d; v.w *= d;
    ((float4*)out)[i] = v;
  }
}

// ---------------- SpMV: out[v] = a*dinv[v]*sum_{e:dst=v} xs[src_e] + bz*z[v]
// xs is PRE-SCALED by dinv[src]. One wave per node, lane holds float2.
__global__ __launch_bounds__(256) void spmv_kernel(
    const float* __restrict__ xs, const float* __restrict__ dinv,
    const int* __restrict__ offsets, const int* __restrict__ csr,
    const float* __restrict__ z, float a, float bz,
    float* __restrict__ out, float* __restrict__ outs, int n) {
  int w = threadIdx.x >> 6, lane = threadIdx.x & 63;
  int node = blockIdx.x * 4 + w;
  if (node >= n) return;
  int beg = offsets[node], end = offsets[node + 1];
  int c = lane * 2;
  float accx = 0.f, accy = 0.f;
  int e2 = beg;
  for (; e2 + 4 <= end; e2 += 4) {
    int s0 = csr[e2], s1 = csr[e2 + 1], s2 = csr[e2 + 2], s3 = csr[e2 + 3];
    float2 a0 = *(const float2*)(xs + (size_t)s0 * NF + c);
    float2 a1 = *(const float2*)(xs + (size_t)s1 * NF + c);
    float2 a2 = *(const float2*)(xs + (size_t)s2 * NF + c);
    float2 a3 = *(const float2*)(xs + (size_t)s3 * NF + c);
    accx += a0.x + a1.x + a2.x + a3.x;
    accy += a0.y + a1.y + a2.y + a3.y;
  }
  for (; e2 < end; ++e2) {
    int s0 = csr[e2];
    float2 a0 = *(const float2*)(xs + (size_t)s0 * NF + c);
    accx += a0.x; accy += a0.y;
  }
  float dv = dinv[node];
  float vx = a * dv * accx, vy = a * dv * accy;
  if (z) {
    float2 zz = *(const float2*)(z + (size_t)node * NF + c);
    vx += bz * zz.x; vy += bz * zz.y;
  }
  float2 vo; vo.x = vx; vo.y = vy;
  *(float2*)(out + (size_t)node * NF + c) = vo;
  if (outs) {
    float2 vs; vs.x = vx * dv; vs.y = vy * dv;
    *(float2*)(outs + (size_t)node * NF + c) = vs;
  }
}

// ---------------- W pre-split + frag-pack ----------------
// W is [NC][K] row-major (original layout). Output: frag-major packed hi/lo bf16:
// Wp[((kunit*NT + nt)*2 + hl)*64 + lane] = 8 bf16, where
//   n = nt*16 + (lane&15), k = kunit*32 + (lane>>4)*8 + j   (B-fragment of mfma_f32_16x16x32_bf16)
__global__ void pack_w_kernel(const float* __restrict__ W, ushort8* __restrict__ Wp, int NT, int K) {
  int f = blockIdx.x * 256 + threadIdx.x;
  int total = (K >> 5) * NT * 2 * 64;
  if (f >= total) return;
  int lane = f & 63;
  int hl = (f >> 6) & 1;
  int rest = f >> 7;
  int nt = rest % NT;
  int kunit = rest / NT;
  int nrow = nt * 16 + (lane & 15);
  int k0 = kunit * 32 + (lane >> 4) * 8;
  const float* srcp = W + (size_t)nrow * K + k0;
  ushort8 v;
#pragma unroll
  for (int j = 0; j < 8; ++j) {
    float x = srcp[j];
    __bf16 h = (__bf16)x;
    if (hl) h = (__bf16)(x - (float)h);
    v[j] = __builtin_bit_cast(unsigned short, h);
  }
  Wp[f] = v;
}

// ---------------- split-bf16 MFMA GEMM ----------------
// out[N][NC] = epi( sum_p Xp[N][128] @ W_p^T + bias ), W packed frag-major (hi/lo).
// 3 MFMA passes per k-chunk: Ah*Bh + Ah*Bl + Al*Bh (split-bf16 ~ f32 accuracy).
// Block: 256 thr = 4 waves (2x2), tile 64 x NC, BK=64. A staged in LDS (f32->split bf16,
// XOR-swizzled b128 frags); B frags loaded directly from packed global (L2-resident).
template<int NC, int NPART>
__global__ __launch_bounds__(256) void mfma_gemm_kernel(
    const float* __restrict__ X0, const float* __restrict__ X1, const float* __restrict__ X2,
    const ushort8* __restrict__ Wp, const float* __restrict__ bias,
    const float* __restrict__ res, float* __restrict__ out, int n, int relu) {
  constexpr int NT    = NC / 16;   // total n-tiles
  constexpr int NT2   = NC / 32;   // n-tiles per wave
  constexpr int NSTEP = NPART * 2; // 64-wide k-steps

  __shared__ float4 AHI[512];   // [64 rows][8 frags] bf16x8, XOR-swizzled
  __shared__ float4 ALO[512];

  int tid = threadIdx.x;
  int lane = tid & 63, wid = tid >> 6;
  int wm = wid >> 1, wn = wid & 1;
  int r0 = blockIdx.x * 64;

  f32x4 acc[2][NT2];
#pragma unroll
  for (int mt = 0; mt < 2; ++mt)
#pragma unroll
    for (int j = 0; j < NT2; ++j) acc[mt][j] = (f32x4)0.f;

  const float* Xarr[3] = {X0, X1, X2};

#pragma unroll
  for (int s = 0; s < NSTEP; ++s) {
    const float* __restrict__ X = Xarr[s >> 1];
    int kin = (s & 1) * 64;
    // ---- stage A: 64 rows x 64 k, f32 -> split bf16 hi/lo, swizzled b128 frags
#pragma unroll
    for (int h = 0; h < 2; ++h) {
      int f = tid + h * 256;
      int row = f >> 3, fc = f & 7;
      int grow = r0 + row;
      float4 v0 = make_float4(0.f, 0.f, 0.f, 0.f);
      float4 v1 = make_float4(0.f, 0.f, 0.f, 0.f);
      if (grow < n) {
        const float4* srcp = (const float4*)(X + (size_t)grow * NF + kin + fc * 8);
        v0 = srcp[0]; v1 = srcp[1];
      }
      float xv[8] = {v0.x, v0.y, v0.z, v0.w, v1.x, v1.y, v1.z, v1.w};
      ushort8 hi, lo;
#pragma unroll
      for (int j2 = 0; j2 < 8; ++j2) {
        __bf16 hh = (__bf16)xv[j2];
        __bf16 ll = (__bf16)(xv[j2] - (float)hh);
        hi[j2] = __builtin_bit_cast(unsigned short, hh);
        lo[j2] = __builtin_bit_cast(unsigned short, ll);
      }
      int idx = row * 8 + (fc ^ (row & 7));
      AHI[idx] = __builtin_bit_cast(float4, hi);
      ALO[idx] = __builtin_bit_cast(float4, lo);
    }
    __syncthreads();
    // ---- compute
#pragma unroll
    for (int ks = 0; ks < 2; ++ks) {
      int kunit = s * 2 + ks;
      bf16x8 ah[2], al[2];
#pragma unroll
      for (int mt = 0; mt < 2; ++mt) {
        int arow = wm * 32 + mt * 16 + (lane & 15);
        int fc = ks * 4 + (lane >> 4);
        int idx = arow * 8 + (fc ^ (arow & 7));
        ah[mt] = __builtin_bit_cast(bf16x8, AHI[idx]);
        al[mt] = __builtin_bit_cast(bf16x8, ALO[idx]);
      }
#pragma unroll
      for (int j = 0; j < NT2; ++j) {
        int nt = wn * NT2 + j;
        const ushort8* bp = Wp + (size_t)(kunit * NT + nt) * 2 * 64 + lane;
        bf16x8 bh = __builtin_bit_cast(bf16x8, bp[0]);
        bf16x8 bl = __builtin_bit_cast(bf16x8, bp[64]);
#pragma unroll
        for (int mt = 0; mt < 2; ++mt) {
          acc[mt][j] = __builtin_amdgcn_mfma_f32_16x16x32_bf16(ah[mt], bh, acc[mt][j], 0, 0, 0);
          acc[mt][j] = __builtin_amdgcn_mfma_f32_16x16x32_bf16(ah[mt], bl, acc[mt][j], 0, 0, 0);
          acc[mt][j] = __builtin_amdgcn_mfma_f32_16x16x32_bf16(al[mt], bh, acc[mt][j], 0, 0, 0);
        }
      }
    }
    __syncthreads();
  }
  // ---- epilogue: C/D layout col=lane&15, row=(lane>>4)*4+i (m89-verified)
#pragma unroll
  for (int mt = 0; mt < 2; ++mt) {
#pragma unroll
    for (int i = 0; i < 4; ++i) {
      int row = r0 + wm * 32 + mt * 16 + (lane >> 4) * 4 + i;
      if (row < n) {
#pragma unroll
        for (int j = 0; j < NT2; ++j) {
          int col = wn * (NC / 2) + j * 16 + (lane & 15);
          float v = acc[mt][j][i] + bias[col];
          if (relu) v = fmaxf(v, 0.f);
          if (res) v += res[(size_t)row * NC + col];
          out[(size_t)row * NC + col] = v;
        }
      }
    }
  }
}

// ---------------- BatchNorm ----------------
__global__ void bn_stats_kernel(const float* __restrict__ x, float* __restrict__ stats, int n) {
  int c = threadIdx.x;   // 128
  float s = 0.f, s2 = 0.f;
  for (int r = blockIdx.x; r < n; r += gridDim.x) {
    float v = x[(size_t)r * NF + c];
    s += v;
    s2 += v * v;
  }
  atomicAdd(&stats[c], s);
  atomicAdd(&stats[NF + c], s2);
}

__global__ void bn_scale_kernel(const float* __restrict__ stats, const float* __restrict__ gamma,
                                const float* __restrict__ beta, float* __restrict__ sc,
                                float* __restrict__ sh, float n) {
  int c = threadIdx.x;   // 128
  float mu = stats[c] / n;
  float var = stats[NF + c] / n - mu * mu;
  float s = gamma[c] * rsqrtf(var + 1e-5f);
  sc[c] = s;
  sh[c] = beta[c] - mu * s;
}

// BN apply in place + also write dinv-scaled copy (gather source for conv2 spmv)
__global__ void bn_apply_kernel(float* __restrict__ x, const float* __restrict__ sc,
                                const float* __restrict__ sh, const float* __restrict__ dinv,
                                float* __restrict__ xscaled, int n) {
  int i = blockIdx.x * 256 + threadIdx.x;   // float4 index
  if (i < n * (NF / 4)) {
    int row = i >> 5;
    int c0 = (i & 31) * 4;
    float4 v = ((const float4*)x)[i];
    v.x = v.x * sc[c0 + 0] + sh[c0 + 0];
    v.y = v.y * sc[c0 + 1] + sh[c0 + 1];
    v.z = v.z * sc[c0 + 2] + sh[c0 + 2];
    v.w = v.w * sc[c0 + 3] + sh[c0 + 3];
    ((float4*)x)[i] = v;
    float d = dinv[row];
    float4 vs; vs.x = v.x * d; vs.y = v.y * d; vs.z = v.z * d; vs.w = v.w * d;
    ((float4*)xscaled)[i] = vs;
  }
}

// ---------------- launcher ----------------
extern "C" void kernel_launch(void* const* d_in, const int* in_sizes, int n_in,
                              void* d_out, int out_size, void* d_ws, size_t ws_size,
                              hipStream_t stream) {
  const float* feat  = (const float*)d_in[0];
  const int*   src   = (const int*)d_in[1];
  const int*   dst   = (const int*)d_in[2];
  const float* W1    = (const float*)d_in[3];
  const float* b1    = (const float*)d_in[4];
  const float* W3    = (const float*)d_in[5];
  const float* b3    = (const float*)d_in[6];
  const float* gamma = (const float*)d_in[7];
  const float* beta  = (const float*)d_in[8];
  const float* Wm1   = (const float*)d_in[9];
  const float* bm1   = (const float*)d_in[10];
  const float* Wm2   = (const float*)d_in[11];
  const float* bm2   = (const float*)d_in[12];
  int n = in_sizes[0] / NF;
  int e = in_sizes[1];

  char* p = (char*)d_ws;
  auto alloc = [&](size_t bytes) {
    char* r = p;
    p += (bytes + 255) & ~size_t(255);
    return r;
  };
  int*   degi     = (int*)alloc((size_t)n * 4);
  float* dinv     = (float*)alloc((size_t)n * 4);
  int*   offsets  = (int*)alloc((size_t)(n + 1) * 4);
  int*   cursor   = (int*)alloc((size_t)n * 4);
  int*   partials = (int*)alloc(256 * 4);
  int*   csr      = (int*)alloc((size_t)e * 4);
  float* stats    = (float*)alloc(256 * 4);
  float* bnsc     = (float*)alloc(128 * 4);
  float* bnsh     = (float*)alloc(128 * 4);
  ushort8* Wp1  = (ushort8*)alloc(12 * 8 * 2 * 64 * 16);   // K=384, NT=8
  ushort8* Wp3  = (ushort8*)alloc(12 * 8 * 2 * 64 * 16);
  ushort8* WpM1 = (ushort8*)alloc(4 * 8 * 2 * 64 * 16);    // K=128, NT=8
  ushort8* WpM2 = (ushort8*)alloc(4 * 4 * 2 * 64 * 16);    // K=128, NT=4
  size_t matb = (size_t)n * NF * 4;
  float* T1   = (float*)alloc(matb);   // T1 buf; later reused as MLP hidden H
  float* T1s  = (float*)alloc(matb);   // dinv-scaled T1 (gather source)
  float* T2   = (float*)alloc(matb);   // also: Fs (scaled feat) before T2 is live
  float* X    = (float*)alloc(matb);   // conv1 out -> BN in place -> x_res
  float* Xs   = (float*)alloc(matb);   // scaled X; later reused as conv2 out Y
  float* Fs = T2;    // alias: feat*dinv, dead before T2 written
  float* Y  = Xs;    // alias: conv2 output, Xs dead before Y written
  float* H  = T1;    // alias: MLP hidden, T1 dead before H written

  hipMemsetAsync(degi, 0, (size_t)n * 4, stream);
  hipMemsetAsync(stats, 0, 256 * 4, stream);

  int eb = ceil_div(e, 256), nb = ceil_div(n, 256);
  int fb = ceil_div(n * (NF / 4), 256);      // float4-grid over matrices
  int sb = ceil_div(n, 4);                   // spmv: 4 nodes/block
  int gb = ceil_div(n, 64);                  // gemm: 64 rows/block

  // degree + dinv + CSR (sorted by dst)
  hist_deg_kernel<<<eb, 256, 0, stream>>>(dst, degi, e);
  dinv_kernel<<<nb, 256, 0, stream>>>(degi, dinv, n);
  scan_partials_kernel<<<nb, 256, 0, stream>>>(degi, partials, n);
  scan_block_kernel<<<1, 256, 0, stream>>>(partials, nb);
  scan_final_kernel<<<nb, 256, 0, stream>>>(degi, partials, offsets, n);
  cursor_init_kernel<<<nb, 256, 0, stream>>>(offsets, cursor, offsets + n, n, e);
  scatter_kernel<<<eb, 256, 0, stream>>>(src, dst, cursor, csr, e);

  // W split+pack (tiny)
  pack_w_kernel<<<48, 256, 0, stream>>>(W1, Wp1, 8, 384);
  pack_w_kernel<<<48, 256, 0, stream>>>(W3, Wp3, 8, 384);
  pack_w_kernel<<<16, 256, 0, stream>>>(Wm1, WpM1, 8, 128);
  pack_w_kernel<<<8, 256, 0, stream>>>(Wm2, WpM2, 4, 128);

  // conv1: T1 = -A^ F ; T2 = -2 A^ T1 - F ; X = relu([F,T1,T2] @ W1^T + b1)
  scale_rows_kernel<<<fb, 256, 0, stream>>>(feat, dinv, Fs, n);
  spmv_kernel<<<sb, 256, 0, stream>>>(Fs, dinv, offsets, csr, nullptr, -1.f, 0.f, T1, T1s, n);
  spmv_kernel<<<sb, 256, 0, stream>>>(T1s, dinv, offsets, csr, feat, -2.f, -1.f, T2, nullptr, n);
  mfma_gemm_kernel<128, 3><<<gb, 256, 0, stream>>>(feat, T1, T2, Wp1, b1, nullptr, X, n, 1);

  // BatchNorm (training stats, biased var), in place; X becomes x_res; Xs = X*dinv
  bn_stats_kernel<<<512, 128, 0, stream>>>(X, stats, n);
  bn_scale_kernel<<<1, 128, 0, stream>>>(stats, gamma, beta, bnsc, bnsh, (float)n);
  bn_apply_kernel<<<fb, 256, 0, stream>>>(X, bnsc, bnsh, dinv, Xs, n);

  // conv2 + residual: Y = relu([X,T1,T2] @ W3^T + b3) + X
  spmv_kernel<<<sb, 256, 0, stream>>>(Xs, dinv, offsets, csr, nullptr, -1.f, 0.f, T1, T1s, n);
  spmv_kernel<<<sb, 256, 0, stream>>>(T1s, dinv, offsets, csr, X, -2.f, -1.f, T2, nullptr, n);
  mfma_gemm_kernel<128, 3><<<gb, 256, 0, stream>>>(X, T1, T2, Wp3, b3, X, Y, n, 1);

  // MLP: H = relu(Y @ Wm1^T + bm1) ; out = H @ Wm2^T + bm2
  mfma_gemm_kernel<128, 1><<<gb, 256, 0, stream>>>(Y, nullptr, nullptr, WpM1, bm1, nullptr, H, n, 1);
  mfma_gemm_kernel<64, 1><<<gb, 256, 0, stream>>>(H, nullptr, nullptr, WpM2, bm2, nullptr, (float*)d_out, n, 0);
}

// Round 3
// 473.480 us; speedup vs baseline: 1.9934x; 1.0721x over previous
//
#include <hip/hip_runtime.h>
#include <hip/hip_bf16.h>
#include <math.h>

#define NF 128   // IN_F == HID == 128

typedef __bf16 bf16x8 __attribute__((ext_vector_type(8)));
typedef unsigned short ushort8 __attribute__((ext_vector_type(8)));
typedef float f32x4 __attribute__((ext_vector_type(4)));

static inline int ceil_div(int a, int b) { return (a + b - 1) / b; }

// ---------------- degree / CSR build ----------------
__global__ void hist_deg_kernel(const int* __restrict__ dst, int* __restrict__ degi, int e) {
  int i = blockIdx.x * 256 + threadIdx.x;
  if (i < e) atomicAdd(&degi[dst[i]], 1);
}

__global__ void scan_partials_kernel(const int* __restrict__ degi, int* __restrict__ partials, int n) {
  __shared__ int sh[256];
  int i = blockIdx.x * 256 + threadIdx.x;
  sh[threadIdx.x] = (i < n) ? degi[i] : 0;
  __syncthreads();
  for (int s = 128; s > 0; s >>= 1) {
    if (threadIdx.x < s) sh[threadIdx.x] += sh[threadIdx.x + s];
    __syncthreads();
  }
  if (threadIdx.x == 0) partials[blockIdx.x] = sh[0];
}

__global__ void scan_block_kernel(int* __restrict__ partials, int nb) {
  __shared__ int sh[256];
  int t = threadIdx.x;
  int v = (t < nb) ? partials[t] : 0;
  sh[t] = v;
  __syncthreads();
  for (int off = 1; off < 256; off <<= 1) {
    int add = (t >= off) ? sh[t - off] : 0;
    __syncthreads();
    sh[t] += add;
    __syncthreads();
  }
  if (t < nb) partials[t] = sh[t] - v;   // exclusive
}

// writes offsets, cursor(=offsets), dinv, and offsets[n]=E
__global__ void scan_final_kernel(const int* __restrict__ degi, const int* __restrict__ partials,
                                  int* __restrict__ offsets, int* __restrict__ cursor,
                                  float* __restrict__ dinv, int n, int e) {
  __shared__ int sh[256];
  int i = blockIdx.x * 256 + threadIdx.x;
  int v = (i < n) ? degi[i] : 0;
  sh[threadIdx.x] = v;
  __syncthreads();
  for (int off = 1; off < 256; off <<= 1) {
    int add = (threadIdx.x >= off) ? sh[threadIdx.x - off] : 0;
    __syncthreads();
    sh[threadIdx.x] += add;
    __syncthreads();
  }
  if (i < n) {
    int o = partials[blockIdx.x] + sh[threadIdx.x] - v;
    offsets[i] = o;
    cursor[i] = o;
    float d = (float)(v > 1 ? v : 1);
    dinv[i] = rsqrtf(d);
  }
  if (i == 0) offsets[n] = e;
}

__global__ void scatter_kernel(const int* __restrict__ src, const int* __restrict__ dst,
                               const float* __restrict__ dinv, int* __restrict__ cursor,
                               int* __restrict__ csr_src, float* __restrict__ csr_w, int e) {
  int i = blockIdx.x * 256 + threadIdx.x;
  if (i < e) {
    int s = src[i];
    int pos = atomicAdd(&cursor[dst[i]], 1);
    csr_src[pos] = s;
    csr_w[pos] = dinv[s];
  }
}

// ---------------- SpMV: out[v] = a*dinv[v]*sum_{e:dst=v} x[src_e]*dinv[src_e] + bz*z[v]
// One wave per node. Lane = [edge-of-pair (lane>>5)][16B col-block (lane&31)].
// csr/csrw streams read via SGPR (readfirstlane base) -> scalar loads; gathers are
// dwordx4 covering 2 edges per instruction.
__global__ __launch_bounds__(256) void spmv_kernel(
    const float* __restrict__ x, const float* __restrict__ dinv,
    const int* __restrict__ offsets, const int* __restrict__ csr,
    const float* __restrict__ csrw,
    const float* __restrict__ z, float a, float bz,
    float* __restrict__ out, int n) {
  int w = threadIdx.x >> 6, lane = threadIdx.x & 63;
  int node = blockIdx.x * 4 + w;
  if (node >= n) return;
  int beg = __builtin_amdgcn_readfirstlane(offsets[node]);
  int end = __builtin_amdgcn_readfirstlane(offsets[node + 1]);
  int eh = lane >> 5;        // which edge of the pair
  int cq = lane & 31;        // float4 slot within the row

  f32x4 acc = (f32x4)0.f;
  int e2 = beg;
  // 8-edge chunks: 4 independent 2-edge dwordx4 gathers
  for (; e2 + 8 <= end; e2 += 8) {
    int si[8]; float wi[8];
#pragma unroll
    for (int t = 0; t < 8; ++t) { si[t] = csr[e2 + t]; wi[t] = csrw[e2 + t]; }
    int   sA = eh ? si[1] : si[0], sB = eh ? si[3] : si[2];
    int   sC = eh ? si[5] : si[4], sD = eh ? si[7] : si[6];
    float wA = eh ? wi[1] : wi[0], wB = eh ? wi[3] : wi[2];
    float wC = eh ? wi[5] : wi[4], wD = eh ? wi[7] : wi[6];
    f32x4 gA = ((const f32x4*)(x + (size_t)sA * NF))[cq];
    f32x4 gB = ((const f32x4*)(x + (size_t)sB * NF))[cq];
    f32x4 gC = ((const f32x4*)(x + (size_t)sC * NF))[cq];
    f32x4 gD = ((const f32x4*)(x + (size_t)sD * NF))[cq];
#pragma unroll
    for (int j = 0; j < 4; ++j) {
      acc[j] += wA * gA[j];
      acc[j] += wB * gB[j];
      acc[j] += wC * gC[j];
      acc[j] += wD * gD[j];
    }
  }
  // remaining pairs
  for (; e2 + 2 <= end; e2 += 2) {
    int s0 = csr[e2], s1 = csr[e2 + 1];
    float w0 = csrw[e2], w1 = csrw[e2 + 1];
    int sA = eh ? s1 : s0;
    float wA = eh ? w1 : w0;
    f32x4 g = ((const f32x4*)(x + (size_t)sA * NF))[cq];
#pragma unroll
    for (int j = 0; j < 4; ++j) acc[j] += wA * g[j];
  }
  // odd leftover edge: first half-wave only
  if (e2 < end && eh == 0) {
    int s0 = csr[e2];
    float w0 = csrw[e2];
    f32x4 g = ((const f32x4*)(x + (size_t)s0 * NF))[cq];
#pragma unroll
    for (int j = 0; j < 4; ++j) acc[j] += w0 * g[j];
  }
  // cross-half reduce (edge 0 + edge 1 partials)
#pragma unroll
  for (int j = 0; j < 4; ++j) acc[j] += __shfl_xor(acc[j], 32);
  if (eh == 0) {
    float dv = dinv[node];
    f32x4 v;
#pragma unroll
    for (int j = 0; j < 4; ++j) v[j] = a * dv * acc[j];
    if (z) {
      f32x4 zz = ((const f32x4*)(z + (size_t)node * NF))[cq];
#pragma unroll
      for (int j = 0; j < 4; ++j) v[j] += bz * zz[j];
    }
    ((f32x4*)(out + (size_t)node * NF))[cq] = v;
  }
}

// ---------------- W pre-split + frag-pack (all 4 weights in one launch) ----------------
// Wp[((kunit*NT + nt)*2 + hl)*64 + lane] = 8 bf16:
//   n = nt*16 + (lane&15), k = kunit*32 + (lane>>4)*8 + j  (B-frag of mfma_f32_16x16x32_bf16)
__device__ __forceinline__ void pack_one(const float* __restrict__ W, ushort8* __restrict__ Wp,
                                         int f, int NT, int K) {
  int lane = f & 63;
  int hl = (f >> 6) & 1;
  int rest = f >> 7;
  int nt = rest % NT;
  int kunit = rest / NT;
  int nrow = nt * 16 + (lane & 15);
  int k0 = kunit * 32 + (lane >> 4) * 8;
  const float* srcp = W + (size_t)nrow * K + k0;
  ushort8 v;
#pragma unroll
  for (int j = 0; j < 8; ++j) {
    float x = srcp[j];
    __bf16 h = (__bf16)x;
    if (hl) h = (__bf16)(x - (float)h);
    v[j] = __builtin_bit_cast(unsigned short, h);
  }
  Wp[f] = v;
}

__global__ void pack_all_kernel(const float* __restrict__ W1, ushort8* __restrict__ P1,
                                const float* __restrict__ W3, ushort8* __restrict__ P3,
                                const float* __restrict__ Wm1, ushort8* __restrict__ PM1,
                                const float* __restrict__ Wm2, ushort8* __restrict__ PM2) {
  int f = blockIdx.x * 256 + threadIdx.x;
  if (f < 12288) pack_one(W1, P1, f, 8, 384);
  else if (f < 24576) pack_one(W3, P3, f - 12288, 8, 384);
  else if (f < 28672) pack_one(Wm1, PM1, f - 24576, 8, 128);
  else if (f < 30720) pack_one(Wm2, PM2, f - 28672, 4, 128);
}

// ---------------- split-bf16 MFMA GEMM ----------------
// out[N][NC] = epi( sum_p Xp[N][128] @ W_p^T + bias ), W packed frag-major (hi/lo).
// 3 MFMA passes per k-chunk: Ah*Bh + Ah*Bl + Al*Bh (split-bf16 ~ f32 accuracy).
template<int NC, int NPART>
__global__ __launch_bounds__(256) void mfma_gemm_kernel(
    const float* __restrict__ X0, const float* __restrict__ X1, const float* __restrict__ X2,
    const ushort8* __restrict__ Wp, const float* __restrict__ bias,
    const float* __restrict__ res, float* __restrict__ out, int n, int relu) {
  constexpr int NT    = NC / 16;   // total n-tiles
  constexpr int NT2   = NC / 32;   // n-tiles per wave
  constexpr int NSTEP = NPART * 2; // 64-wide k-steps

  __shared__ float4 AHI[512];   // [64 rows][8 frags] bf16x8, XOR-swizzled
  __shared__ float4 ALO[512];

  int tid = threadIdx.x;
  int lane = tid & 63, wid = tid >> 6;
  int wm = wid >> 1, wn = wid & 1;
  int r0 = blockIdx.x * 64;

  f32x4 acc[2][NT2];
#pragma unroll
  for (int mt = 0; mt < 2; ++mt)
#pragma unroll
    for (int j = 0; j < NT2; ++j) acc[mt][j] = (f32x4)0.f;

  const float* Xarr[3] = {X0, X1, X2};

#pragma unroll
  for (int s = 0; s < NSTEP; ++s) {
    const float* __restrict__ X = Xarr[s >> 1];
    int kin = (s & 1) * 64;
    // ---- stage A: 64 rows x 64 k, f32 -> split bf16 hi/lo, swizzled b128 frags
#pragma unroll
    for (int h = 0; h < 2; ++h) {
      int f = tid + h * 256;
      int row = f >> 3, fc = f & 7;
      int grow = r0 + row;
      float4 v0 = make_float4(0.f, 0.f, 0.f, 0.f);
      float4 v1 = make_float4(0.f, 0.f, 0.f, 0.f);
      if (grow < n) {
        const float4* srcp = (const float4*)(X + (size_t)grow * NF + kin + fc * 8);
        v0 = srcp[0]; v1 = srcp[1];
      }
      float xv[8] = {v0.x, v0.y, v0.z, v0.w, v1.x, v1.y, v1.z, v1.w};
      ushort8 hi, lo;
#pragma unroll
      for (int j2 = 0; j2 < 8; ++j2) {
        __bf16 hh = (__bf16)xv[j2];
        __bf16 ll = (__bf16)(xv[j2] - (float)hh);
        hi[j2] = __builtin_bit_cast(unsigned short, hh);
        lo[j2] = __builtin_bit_cast(unsigned short, ll);
      }
      int idx = row * 8 + (fc ^ (row & 7));
      AHI[idx] = __builtin_bit_cast(float4, hi);
      ALO[idx] = __builtin_bit_cast(float4, lo);
    }
    __syncthreads();
    // ---- compute
#pragma unroll
    for (int ks = 0; ks < 2; ++ks) {
      int kunit = s * 2 + ks;
      bf16x8 ah[2], al[2];
#pragma unroll
      for (int mt = 0; mt < 2; ++mt) {
        int arow = wm * 32 + mt * 16 + (lane & 15);
        int fc = ks * 4 + (lane >> 4);
        int idx = arow * 8 + (fc ^ (arow & 7));
        ah[mt] = __builtin_bit_cast(bf16x8, AHI[idx]);
        al[mt] = __builtin_bit_cast(bf16x8, ALO[idx]);
      }
#pragma unroll
      for (int j = 0; j < NT2; ++j) {
        int nt = wn * NT2 + j;
        const ushort8* bp = Wp + (size_t)(kunit * NT + nt) * 2 * 64 + lane;
        bf16x8 bh = __builtin_bit_cast(bf16x8, bp[0]);
        bf16x8 bl = __builtin_bit_cast(bf16x8, bp[64]);
#pragma unroll
        for (int mt = 0; mt < 2; ++mt) {
          acc[mt][j] = __builtin_amdgcn_mfma_f32_16x16x32_bf16(ah[mt], bh, acc[mt][j], 0, 0, 0);
          acc[mt][j] = __builtin_amdgcn_mfma_f32_16x16x32_bf16(ah[mt], bl, acc[mt][j], 0, 0, 0);
          acc[mt][j] = __builtin_amdgcn_mfma_f32_16x16x32_bf16(al[mt], bh, acc[mt][j], 0, 0, 0);
        }
      }
    }
    __syncthreads();
  }
  // ---- epilogue: C/D layout col=lane&15, row=(lane>>4)*4+i (m89-verified)
#pragma unroll
  for (int mt = 0; mt < 2; ++mt) {
#pragma unroll
    for (int i = 0; i < 4; ++i) {
      int row = r0 + wm * 32 + mt * 16 + (lane >> 4) * 4 + i;
      if (row < n) {
#pragma unroll
        for (int j = 0; j < NT2; ++j) {
          int col = wn * (NC / 2) + j * 16 + (lane & 15);
          float v = acc[mt][j][i] + bias[col];
          if (relu) v = fmaxf(v, 0.f);
          if (res) v += res[(size_t)row * NC + col];
          out[(size_t)row * NC + col] = v;
        }
      }
    }
  }
}

// ---------------- BatchNorm ----------------
__global__ void bn_stats_kernel(const float* __restrict__ x, float* __restrict__ stats, int n) {
  int c = threadIdx.x;   // 128
  float s = 0.f, s2 = 0.f;
  for (int r = blockIdx.x; r < n; r += gridDim.x) {
    float v = x[(size_t)r * NF + c];
    s += v;
    s2 += v * v;
  }
  atomicAdd(&stats[c], s);
  atomicAdd(&stats[NF + c], s2);
}

__global__ void bn_scale_kernel(const float* __restrict__ stats, const float* __restrict__ gamma,
                                const float* __restrict__ beta, float* __restrict__ sc,
                                float* __restrict__ sh, float n) {
  int c = threadIdx.x;   // 128
  float mu = stats[c] / n;
  float var = stats[NF + c] / n - mu * mu;
  float s = gamma[c] * rsqrtf(var + 1e-5f);
  sc[c] = s;
  sh[c] = beta[c] - mu * s;
}

__global__ void bn_apply_kernel(float* __restrict__ x, const float* __restrict__ sc,
                                const float* __restrict__ sh, int n) {
  int i = blockIdx.x * 256 + threadIdx.x;   // float4 index
  if (i < n * (NF / 4)) {
    int c0 = (i & 31) * 4;
    float4 v = ((const float4*)x)[i];
    v.x = v.x * sc[c0 + 0] + sh[c0 + 0];
    v.y = v.y * sc[c0 + 1] + sh[c0 + 1];
    v.z = v.z * sc[c0 + 2] + sh[c0 + 2];
    v.w = v.w * sc[c0 + 3] + sh[c0 + 3];
    ((float4*)x)[i] = v;
  }
}

// ---------------- launcher ----------------
extern "C" void kernel_launch(void* const* d_in, const int* in_sizes, int n_in,
                              void* d_out, int out_size, void* d_ws, size_t ws_size,
                              hipStream_t stream) {
  const float* feat  = (const float*)d_in[0];
  const int*   src   = (const int*)d_in[1];
  const int*   dst   = (const int*)d_in[2];
  const float* W1    = (const float*)d_in[3];
  const float* b1    = (const float*)d_in[4];
  const float* W3    = (const float*)d_in[5];
  const float* b3    = (const float*)d_in[6];
  const float* gamma = (const float*)d_in[7];
  const float* beta  = (const float*)d_in[8];
  const float* Wm1   = (const float*)d_in[9];
  const float* bm1   = (const float*)d_in[10];
  const float* Wm2   = (const float*)d_in[11];
  const float* bm2   = (const float*)d_in[12];
  int n = in_sizes[0] / NF;
  int e = in_sizes[1];

  char* p = (char*)d_ws;
  auto alloc = [&](size_t bytes) {
    char* r = p;
    p += (bytes + 255) & ~size_t(255);
    return r;
  };
  int*   degi     = (int*)alloc((size_t)n * 4);
  float* dinv     = (float*)alloc((size_t)n * 4);
  int*   offsets  = (int*)alloc((size_t)(n + 1) * 4);
  int*   cursor   = (int*)alloc((size_t)n * 4);
  int*   partials = (int*)alloc(256 * 4);
  int*   csr      = (int*)alloc((size_t)e * 4);
  float* csrw     = (float*)alloc((size_t)e * 4);
  float* stats    = (float*)alloc(256 * 4);
  float* bnsc     = (float*)alloc(128 * 4);
  float* bnsh     = (float*)alloc(128 * 4);
  ushort8* Wp1  = (ushort8*)alloc(12 * 8 * 2 * 64 * 16);   // K=384, NT=8
  ushort8* Wp3  = (ushort8*)alloc(12 * 8 * 2 * 64 * 16);
  ushort8* WpM1 = (ushort8*)alloc(4 * 8 * 2 * 64 * 16);    // K=128, NT=8
  ushort8* WpM2 = (ushort8*)alloc(4 * 4 * 2 * 64 * 16);    // K=128, NT=4
  size_t matb = (size_t)n * NF * 4;
  float* T1 = (float*)alloc(matb);   // Cheb T1; later reused as MLP hidden H
  float* T2 = (float*)alloc(matb);
  float* X  = (float*)alloc(matb);   // conv1 out -> BN in place -> x_res
  float* Y  = (float*)alloc(matb);   // conv2 out + residual
  float* H  = T1;                    // alias: MLP hidden, T1 dead before H written

  hipMemsetAsync(degi, 0, (size_t)n * 4, stream);
  hipMemsetAsync(stats, 0, 256 * 4, stream);

  int eb = ceil_div(e, 256), nb = ceil_div(n, 256);
  int fb = ceil_div(n * (NF / 4), 256);      // float4-grid over matrices
  int sb = ceil_div(n, 4);                   // spmv: 4 nodes/block
  int gb = ceil_div(n, 64);                  // gemm: 64 rows/block

  // degree + dinv + CSR (sorted by dst, weights = dinv[src])
  hist_deg_kernel<<<eb, 256, 0, stream>>>(dst, degi, e);
  scan_partials_kernel<<<nb, 256, 0, stream>>>(degi, partials, n);
  scan_block_kernel<<<1, 256, 0, stream>>>(partials, nb);
  scan_final_kernel<<<nb, 256, 0, stream>>>(degi, partials, offsets, cursor, dinv, n, e);
  scatter_kernel<<<eb, 256, 0, stream>>>(src, dst, dinv, cursor, csr, csrw, e);

  // W split+pack (one launch)
  pack_all_kernel<<<120, 256, 0, stream>>>(W1, Wp1, W3, Wp3, Wm1, WpM1, Wm2, WpM2);

  // conv1: T1 = -A^ F ; T2 = -2 A^ T1 - F ; X = relu([F,T1,T2] @ W1^T + b1)
  spmv_kernel<<<sb, 256, 0, stream>>>(feat, dinv, offsets, csr, csrw, nullptr, -1.f, 0.f, T1, n);
  spmv_kernel<<<sb, 256, 0, stream>>>(T1, dinv, offsets, csr, csrw, feat, -2.f, -1.f, T2, n);
  mfma_gemm_kernel<128, 3><<<gb, 256, 0, stream>>>(feat, T1, T2, Wp1, b1, nullptr, X, n, 1);

  // BatchNorm (training stats, biased var), in place; X becomes x_res
  bn_stats_kernel<<<512, 128, 0, stream>>>(X, stats, n);
  bn_scale_kernel<<<1, 128, 0, stream>>>(stats, gamma, beta, bnsc, bnsh, (float)n);
  bn_apply_kernel<<<fb, 256, 0, stream>>>(X, bnsc, bnsh, n);

  // conv2 + residual: Y = relu([X,T1,T2] @ W3^T + b3) + X
  spmv_kernel<<<sb, 256, 0, stream>>>(X, dinv, offsets, csr, csrw, nullptr, -1.f, 0.f, T1, n);
  spmv_kernel<<<sb, 256, 0, stream>>>(T1, dinv, offsets, csr, csrw, X, -2.f, -1.f, T2, n);
  mfma_gemm_kernel<128, 3><<<gb, 256, 0, stream>>>(X, T1, T2, Wp3, b3, X, Y, n, 1);

  // MLP: H = relu(Y @ Wm1^T + bm1) ; out = H @ Wm2^T + bm2
  mfma_gemm_kernel<128, 1><<<gb, 256, 0, stream>>>(Y, nullptr, nullptr, WpM1, bm1, nullptr, H, n, 1);
  mfma_gemm_kernel<64, 1><<<gb, 256, 0, stream>>>(H, nullptr, nullptr, WpM2, bm2, nullptr, (float*)d_out, n, 0);
}

// Round 4
// 399.350 us; speedup vs baseline: 2.3634x; 1.1856x over previous
//
#include <hip/hip_runtime.h>
#include <hip/hip_bf16.h>
#include <math.h>

#define NF 128   // IN_F == HID == 128

typedef __bf16 bf16x8 __attribute__((ext_vector_type(8)));
typedef unsigned short ushort8 __attribute__((ext_vector_type(8)));
typedef float f32x4 __attribute__((ext_vector_type(4)));
typedef _Float16 half8 __attribute__((ext_vector_type(8)));
typedef _Float16 half4 __attribute__((ext_vector_type(4)));

static inline int ceil_div(int a, int b) { return (a + b - 1) / b; }

// ---------------- degree / CSR build ----------------
__global__ void hist_deg_kernel(const int* __restrict__ dst, int* __restrict__ degi, int e) {
  int i = blockIdx.x * 256 + threadIdx.x;
  if (i < e) atomicAdd(&degi[dst[i]], 1);
}

__global__ void scan_partials_kernel(const int* __restrict__ degi, int* __restrict__ partials, int n) {
  __shared__ int sh[256];
  int i = blockIdx.x * 256 + threadIdx.x;
  sh[threadIdx.x] = (i < n) ? degi[i] : 0;
  __syncthreads();
  for (int s = 128; s > 0; s >>= 1) {
    if (threadIdx.x < s) sh[threadIdx.x] += sh[threadIdx.x + s];
    __syncthreads();
  }
  if (threadIdx.x == 0) partials[blockIdx.x] = sh[0];
}

__global__ void scan_block_kernel(int* __restrict__ partials, int nb) {
  __shared__ int sh[256];
  int t = threadIdx.x;
  int v = (t < nb) ? partials[t] : 0;
  sh[t] = v;
  __syncthreads();
  for (int off = 1; off < 256; off <<= 1) {
    int add = (t >= off) ? sh[t - off] : 0;
    __syncthreads();
    sh[t] += add;
    __syncthreads();
  }
  if (t < nb) partials[t] = sh[t] - v;   // exclusive
}

// writes offsets, cursor(=offsets), dinv, and offsets[n]=E
__global__ void scan_final_kernel(const int* __restrict__ degi, const int* __restrict__ partials,
                                  int* __restrict__ offsets, int* __restrict__ cursor,
                                  float* __restrict__ dinv, int n, int e) {
  __shared__ int sh[256];
  int i = blockIdx.x * 256 + threadIdx.x;
  int v = (i < n) ? degi[i] : 0;
  sh[threadIdx.x] = v;
  __syncthreads();
  for (int off = 1; off < 256; off <<= 1) {
    int add = (threadIdx.x >= off) ? sh[threadIdx.x - off] : 0;
    __syncthreads();
    sh[threadIdx.x] += add;
    __syncthreads();
  }
  if (i < n) {
    int o = partials[blockIdx.x] + sh[threadIdx.x] - v;
    offsets[i] = o;
    cursor[i] = o;
    float d = (float)(v > 1 ? v : 1);
    dinv[i] = rsqrtf(d);
  }
  if (i == 0) offsets[n] = e;
}

__global__ void scatter_kernel(const int* __restrict__ src, const int* __restrict__ dst,
                               int* __restrict__ cursor, int* __restrict__ csr_src, int e) {
  int i = blockIdx.x * 256 + threadIdx.x;
  if (i < e) {
    int pos = atomicAdd(&cursor[dst[i]], 1);
    csr_src[pos] = src[i];
  }
}

// ---------------- scale16: out16[r][c] = fp16(x[r][c] * dinv[r]) ----------------
__global__ void scale16_kernel(const float* __restrict__ x, const float* __restrict__ dinv,
                               _Float16* __restrict__ out16, int n) {
  int i = blockIdx.x * 256 + threadIdx.x;   // float4 index, 32 per row
  if (i < n * (NF / 4)) {
    int row = i >> 5;
    float4 v = ((const float4*)x)[i];
    float d = dinv[row];
    half4 h;
    h[0] = (_Float16)(v.x * d); h[1] = (_Float16)(v.y * d);
    h[2] = (_Float16)(v.z * d); h[3] = (_Float16)(v.w * d);
    ((half4*)out16)[i] = h;
  }
}

// ---------------- SpMV: out[v] = a*dinv[v]*sum_{e:dst=v} xs16[src_e] + bz*z[v]
// xs16 is fp16, PRE-SCALED by dinv[src]. One wave per node.
// Lane = [edge-of-quad (lane>>4)][16B slot of 256B row (lane&15)] -> 4 edges per dwordx4.
// Optional outs16 = fp16(out * dinv[v]) (gather source for the next spmv).
__global__ __launch_bounds__(256) void spmv_kernel(
    const _Float16* __restrict__ xs16, const float* __restrict__ dinv,
    const int* __restrict__ offsets, const int* __restrict__ csr,
    const float* __restrict__ z, float a, float bz,
    float* __restrict__ out, _Float16* __restrict__ outs16, int n) {
  int w = threadIdx.x >> 6, lane = threadIdx.x & 63;
  int node = blockIdx.x * 4 + w;
  if (node >= n) return;
  int beg = __builtin_amdgcn_readfirstlane(offsets[node]);
  int end = __builtin_amdgcn_readfirstlane(offsets[node + 1]);
  int eh = lane >> 4;        // which edge of the quad (0..3)
  int cq = lane & 15;        // half8 slot within the 128-half row

  float acc[8];
#pragma unroll
  for (int j = 0; j < 8; ++j) acc[j] = 0.f;

  int e2 = beg;
  // 8-edge chunks: two independent 4-edge dwordx4 gathers
  for (; e2 + 8 <= end; e2 += 8) {
    int s0 = csr[e2 + eh];
    int s1 = csr[e2 + 4 + eh];
    half8 g0 = ((const half8*)(xs16 + (size_t)s0 * NF))[cq];
    half8 g1 = ((const half8*)(xs16 + (size_t)s1 * NF))[cq];
#pragma unroll
    for (int j = 0; j < 8; ++j) acc[j] += (float)g0[j];
#pragma unroll
    for (int j = 0; j < 8; ++j) acc[j] += (float)g1[j];
  }
  for (; e2 + 4 <= end; e2 += 4) {
    int s0 = csr[e2 + eh];
    half8 g0 = ((const half8*)(xs16 + (size_t)s0 * NF))[cq];
#pragma unroll
    for (int j = 0; j < 8; ++j) acc[j] += (float)g0[j];
  }
  int rem = end - e2;
  if (eh < rem) {
    int s0 = csr[e2 + eh];
    half8 g0 = ((const half8*)(xs16 + (size_t)s0 * NF))[cq];
#pragma unroll
    for (int j = 0; j < 8; ++j) acc[j] += (float)g0[j];
  }
  // reduce across the 4 edge-groups
#pragma unroll
  for (int j = 0; j < 8; ++j) {
    acc[j] += __shfl_xor(acc[j], 16);
    acc[j] += __shfl_xor(acc[j], 32);
  }
  if (eh == 0) {
    float dv = dinv[node];
    float v[8];
#pragma unroll
    for (int j = 0; j < 8; ++j) v[j] = a * dv * acc[j];
    if (z) {
      const f32x4* zp = (const f32x4*)(z + (size_t)node * NF + cq * 8);
      f32x4 z0 = zp[0], z1 = zp[1];
#pragma unroll
      for (int j = 0; j < 4; ++j) { v[j] += bz * z0[j]; v[4 + j] += bz * z1[j]; }
    }
    f32x4 o0, o1;
#pragma unroll
    for (int j = 0; j < 4; ++j) { o0[j] = v[j]; o1[j] = v[4 + j]; }
    f32x4* op = (f32x4*)(out + (size_t)node * NF + cq * 8);
    op[0] = o0; op[1] = o1;
    if (outs16) {
      half8 hv;
#pragma unroll
      for (int j = 0; j < 8; ++j) hv[j] = (_Float16)(v[j] * dv);
      *(half8*)(outs16 + (size_t)node * NF + cq * 8) = hv;
    }
  }
}

// ---------------- W pre-split + frag-pack (all 4 weights in one launch) ----------------
// Wp[((kunit*NT + nt)*2 + hl)*64 + lane] = 8 bf16:
//   n = nt*16 + (lane&15), k = kunit*32 + (lane>>4)*8 + j  (B-frag of mfma_f32_16x16x32_bf16)
__device__ __forceinline__ void pack_one(const float* __restrict__ W, ushort8* __restrict__ Wp,
                                         int f, int NT, int K) {
  int lane = f & 63;
  int hl = (f >> 6) & 1;
  int rest = f >> 7;
  int nt = rest % NT;
  int kunit = rest / NT;
  int nrow = nt * 16 + (lane & 15);
  int k0 = kunit * 32 + (lane >> 4) * 8;
  const float* srcp = W + (size_t)nrow * K + k0;
  ushort8 v;
#pragma unroll
  for (int j = 0; j < 8; ++j) {
    float x = srcp[j];
    __bf16 h = (__bf16)x;
    if (hl) h = (__bf16)(x - (float)h);
    v[j] = __builtin_bit_cast(unsigned short, h);
  }
  Wp[f] = v;
}

__global__ void pack_all_kernel(const float* __restrict__ W1, ushort8* __restrict__ P1,
                                const float* __restrict__ W3, ushort8* __restrict__ P3,
                                const float* __restrict__ Wm1, ushort8* __restrict__ PM1,
                                const float* __restrict__ Wm2, ushort8* __restrict__ PM2) {
  int f = blockIdx.x * 256 + threadIdx.x;
  if (f < 12288) pack_one(W1, P1, f, 8, 384);
  else if (f < 24576) pack_one(W3, P3, f - 12288, 8, 384);
  else if (f < 28672) pack_one(Wm1, PM1, f - 24576, 8, 128);
  else if (f < 30720) pack_one(Wm2, PM2, f - 28672, 4, 128);
}

// ---------------- split-bf16 MFMA GEMM ----------------
// out[N][NC] = epi( sum_p Xp[N][128] @ W_p^T + bias ), W packed frag-major (hi/lo).
// 3 MFMA passes per k-chunk: Ah*Bh + Ah*Bl + Al*Bh (split-bf16 ~ f32 accuracy).
template<int NC, int NPART>
__global__ __launch_bounds__(256) void mfma_gemm_kernel(
    const float* __restrict__ X0, const float* __restrict__ X1, const float* __restrict__ X2,
    const ushort8* __restrict__ Wp, const float* __restrict__ bias,
    const float* __restrict__ res, float* __restrict__ out, int n, int relu) {
  constexpr int NT    = NC / 16;   // total n-tiles
  constexpr int NT2   = NC / 32;   // n-tiles per wave
  constexpr int NSTEP = NPART * 2; // 64-wide k-steps

  __shared__ float4 AHI[512];   // [64 rows][8 frags] bf16x8, XOR-swizzled
  __shared__ float4 ALO[512];

  int tid = threadIdx.x;
  int lane = tid & 63, wid = tid >> 6;
  int wm = wid >> 1, wn = wid & 1;
  int r0 = blockIdx.x * 64;

  f32x4 acc[2][NT2];
#pragma unroll
  for (int mt = 0; mt < 2; ++mt)
#pragma unroll
    for (int j = 0; j < NT2; ++j) acc[mt][j] = (f32x4)0.f;

  const float* Xarr[3] = {X0, X1, X2};

#pragma unroll
  for (int s = 0; s < NSTEP; ++s) {
    const float* __restrict__ X = Xarr[s >> 1];
    int kin = (s & 1) * 64;
    // ---- stage A: 64 rows x 64 k, f32 -> split bf16 hi/lo, swizzled b128 frags
#pragma unroll
    for (int h = 0; h < 2; ++h) {
      int f = tid + h * 256;
      int row = f >> 3, fc = f & 7;
      int grow = r0 + row;
      float4 v0 = make_float4(0.f, 0.f, 0.f, 0.f);
      float4 v1 = make_float4(0.f, 0.f, 0.f, 0.f);
      if (grow < n) {
        const float4* srcp = (const float4*)(X + (size_t)grow * NF + kin + fc * 8);
        v0 = srcp[0]; v1 = srcp[1];
      }
      float xv[8] = {v0.x, v0.y, v0.z, v0.w, v1.x, v1.y, v1.z, v1.w};
      ushort8 hi, lo;
#pragma unroll
      for (int j2 = 0; j2 < 8; ++j2) {
        __bf16 hh = (__bf16)xv[j2];
        __bf16 ll = (__bf16)(xv[j2] - (float)hh);
        hi[j2] = __builtin_bit_cast(unsigned short, hh);
        lo[j2] = __builtin_bit_cast(unsigned short, ll);
      }
      int idx = row * 8 + (fc ^ (row & 7));
      AHI[idx] = __builtin_bit_cast(float4, hi);
      ALO[idx] = __builtin_bit_cast(float4, lo);
    }
    __syncthreads();
    // ---- compute
#pragma unroll
    for (int ks = 0; ks < 2; ++ks) {
      int kunit = s * 2 + ks;
      bf16x8 ah[2], al[2];
#pragma unroll
      for (int mt = 0; mt < 2; ++mt) {
        int arow = wm * 32 + mt * 16 + (lane & 15);
        int fc = ks * 4 + (lane >> 4);
        int idx = arow * 8 + (fc ^ (arow & 7));
        ah[mt] = __builtin_bit_cast(bf16x8, AHI[idx]);
        al[mt] = __builtin_bit_cast(bf16x8, ALO[idx]);
      }
#pragma unroll
      for (int j = 0; j < NT2; ++j) {
        int nt = wn * NT2 + j;
        const ushort8* bp = Wp + (size_t)(kunit * NT + nt) * 2 * 64 + lane;
        bf16x8 bh = __builtin_bit_cast(bf16x8, bp[0]);
        bf16x8 bl = __builtin_bit_cast(bf16x8, bp[64]);
#pragma unroll
        for (int mt = 0; mt < 2; ++mt) {
          acc[mt][j] = __builtin_amdgcn_mfma_f32_16x16x32_bf16(ah[mt], bh, acc[mt][j], 0, 0, 0);
          acc[mt][j] = __builtin_amdgcn_mfma_f32_16x16x32_bf16(ah[mt], bl, acc[mt][j], 0, 0, 0);
          acc[mt][j] = __builtin_amdgcn_mfma_f32_16x16x32_bf16(al[mt], bh, acc[mt][j], 0, 0, 0);
        }
      }
    }
    __syncthreads();
  }
  // ---- epilogue: C/D layout col=lane&15, row=(lane>>4)*4+i (m89-verified)
#pragma unroll
  for (int mt = 0; mt < 2; ++mt) {
#pragma unroll
    for (int i = 0; i < 4; ++i) {
      int row = r0 + wm * 32 + mt * 16 + (lane >> 4) * 4 + i;
      if (row < n) {
#pragma unroll
        for (int j = 0; j < NT2; ++j) {
          int col = wn * (NC / 2) + j * 16 + (lane & 15);
          float v = acc[mt][j][i] + bias[col];
          if (relu) v = fmaxf(v, 0.f);
          if (res) v += res[(size_t)row * NC + col];
          out[(size_t)row * NC + col] = v;
        }
      }
    }
  }
}

// ---------------- BatchNorm ----------------
__global__ void bn_stats_kernel(const float* __restrict__ x, float* __restrict__ stats, int n) {
  int c = threadIdx.x;   // 128
  float s = 0.f, s2 = 0.f;
  for (int r = blockIdx.x; r < n; r += gridDim.x) {
    float v = x[(size_t)r * NF + c];
    s += v;
    s2 += v * v;
  }
  atomicAdd(&stats[c], s);
  atomicAdd(&stats[NF + c], s2);
}

__global__ void bn_scale_kernel(const float* __restrict__ stats, const float* __restrict__ gamma,
                                const float* __restrict__ beta, float* __restrict__ sc,
                                float* __restrict__ sh, float n) {
  int c = threadIdx.x;   // 128
  float mu = stats[c] / n;
  float var = stats[NF + c] / n - mu * mu;
  float s = gamma[c] * rsqrtf(var + 1e-5f);
  sc[c] = s;
  sh[c] = beta[c] - mu * s;
}

// BN apply in place + emit fp16 dinv-scaled copy (gather source for conv2)
__global__ void bn_apply_kernel(float* __restrict__ x, const float* __restrict__ sc,
                                const float* __restrict__ sh, const float* __restrict__ dinv,
                                _Float16* __restrict__ xs16, int n) {
  int i = blockIdx.x * 256 + threadIdx.x;   // float4 index
  if (i < n * (NF / 4)) {
    int row = i >> 5;
    int c0 = (i & 31) * 4;
    float4 v = ((const float4*)x)[i];
    v.x = v.x * sc[c0 + 0] + sh[c0 + 0];
    v.y = v.y * sc[c0 + 1] + sh[c0 + 1];
    v.z = v.z * sc[c0 + 2] + sh[c0 + 2];
    v.w = v.w * sc[c0 + 3] + sh[c0 + 3];
    ((float4*)x)[i] = v;
    float d = dinv[row];
    half4 h;
    h[0] = (_Float16)(v.x * d); h[1] = (_Float16)(v.y * d);
    h[2] = (_Float16)(v.z * d); h[3] = (_Float16)(v.w * d);
    ((half4*)xs16)[i] = h;
  }
}

// ---------------- launcher ----------------
extern "C" void kernel_launch(void* const* d_in, const int* in_sizes, int n_in,
                              void* d_out, int out_size, void* d_ws, size_t ws_size,
                              hipStream_t stream) {
  const float* feat  = (const float*)d_in[0];
  const int*   src   = (const int*)d_in[1];
  const int*   dst   = (const int*)d_in[2];
  const float* W1    = (const float*)d_in[3];
  const float* b1    = (const float*)d_in[4];
  const float* W3    = (const float*)d_in[5];
  const float* b3    = (const float*)d_in[6];
  const float* gamma = (const float*)d_in[7];
  const float* beta  = (const float*)d_in[8];
  const float* Wm1   = (const float*)d_in[9];
  const float* bm1   = (const float*)d_in[10];
  const float* Wm2   = (const float*)d_in[11];
  const float* bm2   = (const float*)d_in[12];
  int n = in_sizes[0] / NF;
  int e = in_sizes[1];

  char* p = (char*)d_ws;
  auto alloc = [&](size_t bytes) {
    char* r = p;
    p += (bytes + 255) & ~size_t(255);
    return r;
  };
  int*   degi     = (int*)alloc((size_t)n * 4);
  float* dinv     = (float*)alloc((size_t)n * 4);
  int*   offsets  = (int*)alloc((size_t)(n + 1) * 4);
  int*   cursor   = (int*)alloc((size_t)n * 4);
  int*   partials = (int*)alloc(256 * 4);
  int*   csr      = (int*)alloc((size_t)e * 4);
  float* stats    = (float*)alloc(256 * 4);
  float* bnsc     = (float*)alloc(128 * 4);
  float* bnsh     = (float*)alloc(128 * 4);
  ushort8* Wp1  = (ushort8*)alloc(12 * 8 * 2 * 64 * 16);   // K=384, NT=8
  ushort8* Wp3  = (ushort8*)alloc(12 * 8 * 2 * 64 * 16);
  ushort8* WpM1 = (ushort8*)alloc(4 * 8 * 2 * 64 * 16);    // K=128, NT=8
  ushort8* WpM2 = (ushort8*)alloc(4 * 4 * 2 * 64 * 16);    // K=128, NT=4
  size_t matb = (size_t)n * NF * 4;
  float* T1 = (float*)alloc(matb);   // Cheb T1; later reused as MLP hidden H
  float* T2 = (float*)alloc(matb);
  float* X  = (float*)alloc(matb);   // conv1 out -> BN in place -> x_res
  float* Y  = (float*)alloc(matb);   // conv2 out + residual
  _Float16* xsA  = (_Float16*)alloc((size_t)n * NF * 2);  // Fs16 then Xs16
  _Float16* xsB  = (_Float16*)alloc((size_t)n * NF * 2);  // T1s16 (both convs)
  float* H  = T1;                    // alias: MLP hidden, T1 dead before H written

  hipMemsetAsync(degi, 0, (size_t)n * 4, stream);
  hipMemsetAsync(stats, 0, 256 * 4, stream);

  int eb = ceil_div(e, 256), nb = ceil_div(n, 256);
  int fb = ceil_div(n * (NF / 4), 256);      // float4-grid over matrices
  int sb = ceil_div(n, 4);                   // spmv: 4 nodes/block
  int gb = ceil_div(n, 64);                  // gemm: 64 rows/block

  // degree + dinv + CSR (sorted by dst)
  hist_deg_kernel<<<eb, 256, 0, stream>>>(dst, degi, e);
  scan_partials_kernel<<<nb, 256, 0, stream>>>(degi, partials, n);
  scan_block_kernel<<<1, 256, 0, stream>>>(partials, nb);
  scan_final_kernel<<<nb, 256, 0, stream>>>(degi, partials, offsets, cursor, dinv, n, e);
  scatter_kernel<<<eb, 256, 0, stream>>>(src, dst, cursor, csr, e);

  // W split+pack (one launch)
  pack_all_kernel<<<120, 256, 0, stream>>>(W1, Wp1, W3, Wp3, Wm1, WpM1, Wm2, WpM2);

  // conv1: T1 = -A^ F ; T2 = -2 A^ T1 - F ; X = relu([F,T1,T2] @ W1^T + b1)
  scale16_kernel<<<fb, 256, 0, stream>>>(feat, dinv, xsA, n);
  spmv_kernel<<<sb, 256, 0, stream>>>(xsA, dinv, offsets, csr, nullptr, -1.f, 0.f, T1, xsB, n);
  spmv_kernel<<<sb, 256, 0, stream>>>(xsB, dinv, offsets, csr, feat, -2.f, -1.f, T2, nullptr, n);
  mfma_gemm_kernel<128, 3><<<gb, 256, 0, stream>>>(feat, T1, T2, Wp1, b1, nullptr, X, n, 1);

  // BatchNorm (training stats, biased var), in place; X becomes x_res; xsA = fp16(X*dinv)
  bn_stats_kernel<<<512, 128, 0, stream>>>(X, stats, n);
  bn_scale_kernel<<<1, 128, 0, stream>>>(stats, gamma, beta, bnsc, bnsh, (float)n);
  bn_apply_kernel<<<fb, 256, 0, stream>>>(X, bnsc, bnsh, dinv, xsA, n);

  // conv2 + residual: Y = relu([X,T1,T2] @ W3^T + b3) + X
  spmv_kernel<<<sb, 256, 0, stream>>>(xsA, dinv, offsets, csr, nullptr, -1.f, 0.f, T1, xsB, n);
  spmv_kernel<<<sb, 256, 0, stream>>>(xsB, dinv, offsets, csr, X, -2.f, -1.f, T2, nullptr, n);
  mfma_gemm_kernel<128, 3><<<gb, 256, 0, stream>>>(X, T1, T2, Wp3, b3, X, Y, n, 1);

  // MLP: H = relu(Y @ Wm1^T + bm1) ; out = H @ Wm2^T + bm2
  mfma_gemm_kernel<128, 1><<<gb, 256, 0, stream>>>(Y, nullptr, nullptr, WpM1, bm1, nullptr, H, n, 1);
  mfma_gemm_kernel<64, 1><<<gb, 256, 0, stream>>>(H, nullptr, nullptr, WpM2, bm2, nullptr, (float*)d_out, n, 0);
}